// Round 1
// 405.047 us; speedup vs baseline: 1.1764x; 1.1764x over previous
//
#include <hip/hip_runtime.h>

#define FBANK_MEAN 15.41663f
#define FBANK_STD  6.55582f

constexpr int Bb   = 32;
constexpr int T    = 3200;
constexpr int D    = 128;
constexpr int C    = 512;    // embed_dim
constexpr int QD   = 256;    // quant_dim
constexpr int QN   = 1024;   // quant_n
constexpr int Tp   = 200;
constexpr int Fp   = 8;
constexpr int NTOK = Tp * Fp;     // 1600 tokens per batch
constexpr int TOKS = Bb * NTOK;   // 51200

typedef float v4fe __attribute__((ext_vector_type(4)));
typedef float f32x4 __attribute__((ext_vector_type(4)));
typedef _Float16 h16x4 __attribute__((ext_vector_type(4)));
typedef _Float16 h16x8 __attribute__((ext_vector_type(8)));

#define V4(p) (*(const v4fe*)(p))

// fused_m shared-memory layout (dynamic, 68880 B total):
//   AH  [0      , 32768)  : 64 tok x 256 k  f16 hi  (XOR-swizzled rows)
//   AL  [32768  , 65536)  : 64 tok x 256 k  f16 lo
//   q1v [65536  , 66560)  : per-quarter best      [4][64] f32
//   q1i [66560  , 67584)  : per-quarter best idx  [4][64] i32
//   q2v [67584  , 68608)  : per-quarter second    [4][64] f32
//   flg [68608  , 68864)  : flagged-token list    [64] i32
//   nf  [68864  , 68868)  : flag count
constexpr int SMEM_BYTES = 68880;

// ---------------------------------------------------------------------------
// prep_a: [0,32): cbt transpose-normalize, 32 codes/block (R12-verified).
//         [32,288): M'[k][q] = sum_c W[c][k]proj[c][q]
//                              - mean_c(W[c][k]) * colsum(proj)[q]
//         288: embed_len.  (unchanged from the 463us session)
__global__ void prep_a(const float* __restrict__ w, const float* __restrict__ proj,
                       const float* __restrict__ cb, const int* __restrict__ ilens,
                       float* __restrict__ Mp, float* __restrict__ cbt,
                       int* __restrict__ out_len) {
    const int bid = blockIdx.x, tid = threadIdx.x;
    if (bid < 32) {
        __shared__ float tile[32 * 257];    // padded stride: conflict-free
        __shared__ float nrm[32];
        const int k0 = bid * 32;
        const int lane = tid & 63, wv = tid >> 6;
        #pragma unroll 4
        for (int r = 0; r < 32; ++r)
            tile[r * 257 + tid] = cb[(size_t)(k0 + r) * QD + tid];
        __syncthreads();
        for (int c = 0; c < 8; ++c) {       // wave wv -> codes wv*8..+7
            int r = wv * 8 + c;
            float s = 0.f;
            #pragma unroll
            for (int m = 0; m < 4; ++m) {
                float v = tile[r * 257 + lane + 64 * m];
                s += v * v;
            }
            #pragma unroll
            for (int off = 32; off >= 1; off >>= 1) s += __shfl_xor(s, off);
            if (lane == 0) nrm[r] = rsqrtf(s + 1e-12f);
        }
        __syncthreads();
        const int c = tid & 31;
        #pragma unroll 4
        for (int it = 0; it < 32; ++it) {   // 8 d-rows x 32 codes per iter
            int d = it * 8 + (tid >> 5);
            cbt[d * QN + k0 + c] = tile[c * 257 + d] * nrm[c];
        }
    } else if (bid < 288) {
        int k = bid - 32;                   // patch-element row of M'
        int q = tid;
        float dot = 0.f, wsum = 0.f, psum = 0.f;
        #pragma unroll 4
        for (int cc = 0; cc < C; ++cc) {
            float wv_ = w[cc * 256 + k];    // wave-uniform (s_load, pipelined)
            float pv  = proj[cc * QD + q];  // coalesced
            dot  += wv_ * pv;
            wsum += wv_;
            psum += pv;
        }
        Mp[k * 256 + q] = dot - (wsum * (1.0f / 512.0f)) * psum;
    } else {
        if (tid < Bb) {
            int cnt = ilens[tid] >> 4;
            if (cnt > Tp) cnt = Tp;
            if (cnt < 0) cnt = 0;
            out_len[tid] = Fp * cnt;
        }
    }
}

// ---------------------------------------------------------------------------
// prep_b: G = M'(256x256) x cbt(256x1024), emitted as CODE-MAJOR f16 split:
//   Gh[n][k] = (f16)G[k][n];  Gl[n][k] = (f16)(G[k][n] - (float)Gh[n][k])
// (fp32 G array dropped; h+l reconstructs it to 2^-22 for the fallback path)
__global__ void prep_b(const float* __restrict__ Mp, const float* __restrict__ cbt,
                       _Float16* __restrict__ Gh, _Float16* __restrict__ Gl) {
    __shared__ __align__(16) float mt[16 * 256];   // 16 KB M' tile
    const int tid = threadIdx.x;
    const int kt = blockIdx.x >> 4;      // k-tile 0..15
    const int ct = blockIdx.x & 15;      // code-tile 0..15
    const int k0 = kt * 16;
    const int n  = ct * 64 + (tid & 63); // this thread's code
    const int wv = tid >> 6;             // wave -> 4 k-rows
    #pragma unroll
    for (int r = 0; r < 16; ++r)
        mt[r * 256 + tid] = Mp[(size_t)(k0 + r) * 256 + tid];
    __syncthreads();
    float acc[4] = {0.f, 0.f, 0.f, 0.f};
    for (int d4 = 0; d4 < 64; ++d4) {
        const int db = d4 * 4;
        float c0 = cbt[(size_t)(db + 0) * QN + n];   // coalesced across lane
        float c1 = cbt[(size_t)(db + 1) * QN + n];
        float c2 = cbt[(size_t)(db + 2) * QN + n];
        float c3 = cbt[(size_t)(db + 3) * QN + n];
        #pragma unroll
        for (int j = 0; j < 4; ++j) {
            v4fe m = V4(&mt[(wv * 4 + j) * 256 + db]);  // LDS broadcast b128
            acc[j] += m.x * c0;
            acc[j] += m.y * c1;
            acc[j] += m.z * c2;
            acc[j] += m.w * c3;
        }
    }
    // f16 hi/lo split, code-major store (8 B contiguous per thread)
    h16x4 h, l;
    #pragma unroll
    for (int j = 0; j < 4; ++j) {
        float v = acc[j];
        _Float16 hh = (_Float16)v;
        h[j] = hh;
        l[j] = (_Float16)(v - (float)hh);
    }
    size_t o = (size_t)n * 256 + (size_t)(k0 + wv * 4);
    *(h16x4*)(Gh + o) = h;
    *(h16x4*)(Gl + o) = l;
}

// ---------------------------------------------------------------------------
// fused_m: patch staging (f16x2 split, swizzled LDS) -> sims via
// mfma_f32_16x16x32_f16, 3-term split-precision -> top-2 argmax ->
// fp32 fallback for near-ties (gap < TAU).
//
// Block = 64 tokens (8 time-patches x 8 freq), 4 waves = 4 code-quarters.
// Per wave: 16 n-tiles in 4 groups of 4; per ks: 8 B-frags (global, L2) +
// 8 A-frags (LDS) + 48 MFMAs.  MFMA floor ~39 us chip-wide.
__global__ __launch_bounds__(256, 2) void fused_m(
    const float* __restrict__ xs,        // B*T*D fp32
    const _Float16* __restrict__ Gh,     // 1024 x 256 code-major f16 hi
    const _Float16* __restrict__ Gl,     // 1024 x 256 code-major f16 lo
    int* __restrict__ out_ind)           // TOKS
{
    extern __shared__ char smem[];
    _Float16* AH = (_Float16*)smem;
    _Float16* AL = (_Float16*)(smem + 32768);
    float*    q1v = (float*)(smem + 65536);
    int*      q1i = (int*)  (smem + 66560);
    float*    q2v = (float*)(smem + 67584);
    int*      flg = (int*)  (smem + 68608);
    int*      nf  = (int*)  (smem + 68864);
    float*    redv = q1v;                // overlay: q arrays dead by fallback
    int*      redi = q1i;

    const int tid  = threadIdx.x;
    const int lane = tid & 63;
    const int cq   = tid >> 6;           // wave = code quarter
    const int g    = lane >> 4;          // k-group 0..3
    const int r15  = lane & 15;

    const int bid = blockIdx.x;
    const int b   = bid / 25;
    const int tp0 = (bid % 25) * 8;      // first time-patch of this block
    const int g0  = b * NTOK + tp0 * 8;  // first global token index

    if (tid == 0) *nf = 0;

    // ---- 1. stage 64 tokens: fp32 -> (hi,lo) f16 into swizzled LDS --------
    {
        const v4fe* src = (const v4fe*)(xs + ((size_t)b * T + (size_t)tp0 * 16) * D);
        const float inv = 1.0f / (2.0f * FBANK_STD);
        #pragma unroll
        for (int r = 0; r < 16; ++r) {
            int f4  = r * 256 + tid;          // v4 index into 128x128 chunk
            v4fe v  = (src[f4] - FBANK_MEAN) * inv;
            int row = f4 >> 5;                // time row 0..127
            int d0  = (f4 & 31) << 2;         // freq col 0..124
            int t   = ((row >> 4) << 3) + (d0 >> 4);   // token 0..63
            int k0  = ((row & 15) << 4) + (d0 & 15);   // kh*16+kw
            h16x4 h, l;
            #pragma unroll
            for (int j = 0; j < 4; ++j) {
                float x = v[j];
                _Float16 hh = (_Float16)x;
                h[j] = hh;
                l[j] = (_Float16)(x - (float)hh);
            }
            int off = (t * 512 + k0 * 2) ^ ((t & 7) << 4);  // G4 XOR swizzle
            *(h16x4*)((char*)AH + off) = h;
            *(h16x4*)((char*)AL + off) = l;
        }
    }
    __syncthreads();

    // ---- 2. split-precision MFMA + per-lane top-2 --------------------------
    float b1[16], b2[16]; int i1[16];
    #pragma unroll
    for (int s = 0; s < 16; ++s) { b1[s] = -3.4e38f; b2[s] = -3.4e38f; i1[s] = 0; }

    const int swz = (r15 & 7) << 4;
    const _Float16* gbase = Gh + (size_t)(cq * 256 + r15) * 256 + g * 8;
    const _Float16* lbase = Gl + (size_t)(cq * 256 + r15) * 256 + g * 8;

    for (int ntg = 0; ntg < 4; ++ntg) {
        f32x4 acc[4][4];
        #pragma unroll
        for (int nt = 0; nt < 4; ++nt)
            #pragma unroll
            for (int mt = 0; mt < 4; ++mt)
                acc[nt][mt] = (f32x4){0.f, 0.f, 0.f, 0.f};

        #pragma unroll 2
        for (int ks = 0; ks < 8; ++ks) {
            h16x8 Bh[4], Bl[4];
            #pragma unroll
            for (int nt = 0; nt < 4; ++nt) {
                size_t o = (size_t)(ntg * 64 + nt * 16) * 256 + ks * 32;
                Bh[nt] = *(const h16x8*)(gbase + o);
                Bl[nt] = *(const h16x8*)(lbase + o);
            }
            #pragma unroll
            for (int mt = 0; mt < 4; ++mt) {
                int off = ((mt * 16 + r15) * 512 + ks * 64 + g * 16) ^ swz;
                h16x8 ah = *(const h16x8*)((const char*)AH + off);
                h16x8 al = *(const h16x8*)((const char*)AL + off);
                #pragma unroll
                for (int nt = 0; nt < 4; ++nt) {
                    acc[nt][mt] = __builtin_amdgcn_mfma_f32_16x16x32_f16(ah, Bh[nt], acc[nt][mt], 0, 0, 0);
                    acc[nt][mt] = __builtin_amdgcn_mfma_f32_16x16x32_f16(ah, Bl[nt], acc[nt][mt], 0, 0, 0);
                    acc[nt][mt] = __builtin_amdgcn_mfma_f32_16x16x32_f16(al, Bh[nt], acc[nt][mt], 0, 0, 0);
                }
            }
        }
        // top-2 update: lane holds col r15 of tile (ntg,nt); row=token
        #pragma unroll
        for (int nt = 0; nt < 4; ++nt) {
            int idx = cq * 256 + (ntg * 4 + nt) * 16 + r15;
            #pragma unroll
            for (int mt = 0; mt < 4; ++mt)
                #pragma unroll
                for (int rg = 0; rg < 4; ++rg) {
                    float v = acc[nt][mt][rg];
                    int s = mt * 4 + rg;
                    if (v > b1[s]) { b2[s] = b1[s]; b1[s] = v; i1[s] = idx; }
                    else if (v > b2[s]) b2[s] = v;
                }
        }
    }

    // ---- 3. merge top-2 across the 16 lanes sharing each token ------------
    #pragma unroll
    for (int s = 0; s < 16; ++s) {
        float v1 = b1[s], v2 = b2[s]; int ii = i1[s];
        #pragma unroll
        for (int off = 8; off >= 1; off >>= 1) {
            float ov  = __shfl_xor(v1, off);
            int   oi  = __shfl_xor(ii, off);
            float ov2 = __shfl_xor(v2, off);
            float nb2 = fmaxf(fminf(v1, ov), fmaxf(v2, ov2));
            if (ov > v1 || (ov == v1 && oi < ii)) { v1 = ov; ii = oi; }
            v2 = nb2;
        }
        if (r15 == 0) {
            int t = (s >> 2) * 16 + g * 4 + (s & 3);   // mt*16 + g*4 + rg
            q1v[cq * 64 + t] = v1;
            q1i[cq * 64 + t] = ii;
            q2v[cq * 64 + t] = v2;
        }
    }
    __syncthreads();

    // ---- 4. combine quarters; flag near-ties for exact fallback -----------
    const float TAU = 1e-3f;   // >>500x the f16x2 error bound (~2e-6)
    if (tid < 64) {
        int t = tid;
        float B1 = q1v[t]; int I1 = q1i[t]; float B2 = q2v[t];
        #pragma unroll
        for (int w = 1; w < 4; ++w) {
            float v  = q1v[w * 64 + t];
            int   ii = q1i[w * 64 + t];
            float v2 = q2v[w * 64 + t];
            float nb2 = fmaxf(fminf(B1, v), fmaxf(B2, v2));
            if (v > B1 || (v == B1 && ii < I1)) { B1 = v; I1 = ii; }
            B2 = nb2;
        }
        if (B1 - B2 < TAU) {
            int p = atomicAdd(nf, 1);
            flg[p] = t;
        } else {
            out_ind[g0 + t] = I1;
        }
    }
    __syncthreads();

    // ---- 5. fp32 fallback for flagged tokens (rare: ~250/51200 expected) --
    const int nflag = *nf;
    for (int i = 0; i < nflag; ++i) {
        const int t = flg[i];
        const int tswz = (t & 7) << 4;
        float sj[4] = {0.f, 0.f, 0.f, 0.f};
        #pragma unroll 4
        for (int k8 = 0; k8 < 32; ++k8) {
            int off = (t * 512 + k8 * 16) ^ tswz;
            h16x8 xh = *(const h16x8*)((const char*)AH + off);
            h16x8 xl = *(const h16x8*)((const char*)AL + off);
            float x[8];
            #pragma unroll
            for (int j = 0; j < 8; ++j) x[j] = (float)xh[j] + (float)xl[j];
            #pragma unroll
            for (int jc = 0; jc < 4; ++jc) {
                int cc = tid + jc * 256;
                h16x8 gh = *(const h16x8*)(Gh + (size_t)cc * 256 + k8 * 8);
                h16x8 gl = *(const h16x8*)(Gl + (size_t)cc * 256 + k8 * 8);
                #pragma unroll
                for (int j = 0; j < 8; ++j)
                    sj[jc] += x[j] * ((float)gh[j] + (float)gl[j]);
            }
        }
        // local argmax over this thread's 4 codes (ascending -> strict >)
        float bv = sj[0]; int bi = tid;
        #pragma unroll
        for (int jc = 1; jc < 4; ++jc)
            if (sj[jc] > bv) { bv = sj[jc]; bi = tid + jc * 256; }
        redv[tid] = bv; redi[tid] = bi;
        __syncthreads();
        if (tid < 64) {
            float v = redv[tid]; int ix = redi[tid];
            #pragma unroll
            for (int w = 1; w < 4; ++w) {
                float ov = redv[tid + w * 64]; int oi = redi[tid + w * 64];
                if (ov > v || (ov == v && oi < ix)) { v = ov; ix = oi; }
            }
            #pragma unroll
            for (int off = 32; off >= 1; off >>= 1) {
                float ov = __shfl_xor(v, off); int oi = __shfl_xor(ix, off);
                if (ov > v || (ov == v && oi < ix)) { v = ov; ix = oi; }
            }
            if (tid == 0) out_ind[g0 + t] = ix;
        }
        __syncthreads();
    }
}

// ---------------------------------------------------------------------------
extern "C" void kernel_launch(void* const* d_in, const int* in_sizes, int n_in,
                              void* d_out, int out_size, void* d_ws, size_t ws_size,
                              hipStream_t stream) {
    const float* xs       = (const float*)d_in[0];   // (32,3200,128) f32
    const int*   ilens    = (const int*)  d_in[1];   // (32,) i32
    const float* conv_w   = (const float*)d_in[2];   // (512,1,16,16) f32
    const float* proj     = (const float*)d_in[3];   // (512,256) f32
    const float* codebook = (const float*)d_in[4];   // (1024,256) f32
    int* out = (int*)d_out;                          // 51200 ind + 32 len

    // Workspace 2.25 MB (same footprint as the verified 463us session):
    float*    cbt = (float*)d_ws;                    // 256x1024 = 1 MB
    float*    Mp  = cbt + QD * QN;                   // 256x256  = 256 KB
    _Float16* Gh  = (_Float16*)(Mp + 256 * 256);     // 1024x256 = 512 KB
    _Float16* Gl  = Gh + (size_t)QN * 256;           // 1024x256 = 512 KB

    prep_a<<<289, 256, 0, stream>>>(conv_w, proj, codebook, ilens,
                                    Mp, cbt, out + TOKS);
    prep_b<<<256, 256, 0, stream>>>(Mp, cbt, Gh, Gl);

    (void)hipFuncSetAttribute((const void*)fused_m,
                              hipFuncAttributeMaxDynamicSharedMemorySize,
                              SMEM_BYTES);
    fused_m<<<TOKS / 64, 256, SMEM_BYTES, stream>>>(xs, Gh, Gl, out);
}